// Round 16
// baseline (265.680 us; speedup 1.0000x reference)
//
#include <hip/hip_runtime.h>

typedef __bf16 bf16;
typedef __bf16 v8bf __attribute__((ext_vector_type(8)));
typedef __bf16 v4bf __attribute__((ext_vector_type(4)));
typedef float  v4f  __attribute__((ext_vector_type(4)));

#define MFMA16(a,b,c) __builtin_amdgcn_mfma_f32_16x16x32_bf16((a),(b),(c),0,0,0)

// B=2, S=2048, D=1024, H=16, DK=64
static constexpr int Sq = 2048;
static constexpr size_t NI = 4194304;  // B*S*D
static constexpr size_t NW = 1048576;  // D*D

__device__ __forceinline__ void gld_lds16(const void* g, void* l) {
  __builtin_amdgcn_global_load_lds(
      (__attribute__((address_space(1))) unsigned int*)g,
      (__attribute__((address_space(3))) unsigned int*)l,
      16, 0, 0);
}

// bare v_exp_f32 (2^x) via compiler intrinsic: no libm guards, hazard handled.
__device__ __forceinline__ float exp2_raw(float x) {
  return __builtin_amdgcn_exp2f(x);
}

// ---------------- convert fp32 -> bf16 (q,k,v,wq,wk,wv,wo) ----------------
__global__ __launch_bounds__(256) void convert_kernel(
    const float* __restrict__ q, const float* __restrict__ k, const float* __restrict__ v,
    const float* __restrict__ wq, const float* __restrict__ wk,
    const float* __restrict__ wv, const float* __restrict__ wo,
    bf16* __restrict__ dst)
{
  const int NI4 = 1048576;  // NI/4 = 2^20
  const int NW4 = 262144;   // NW/4 = 2^18
  int idx = blockIdx.x * 256 + threadIdx.x;   // total 4194304
  const float* src; size_t dstoff; int local;
  if (idx < 3 * NI4) {
    int a = idx >> 20; local = idx & (NI4 - 1);
    src = (a == 0) ? q : ((a == 1) ? k : v);
    dstoff = (size_t)a * NI;
  } else {
    int t = idx - 3 * NI4;
    int a = t >> 18; local = t & (NW4 - 1);
    src = (a == 0) ? wq : ((a == 1) ? wk : ((a == 2) ? wv : wo));
    dstoff = 3 * NI + (size_t)a * NW;
  }
  float4 f = ((const float4*)src)[local];
  v4bf hv = { (bf16)f.x, (bf16)f.y, (bf16)f.z, (bf16)f.w };
  *(v4bf*)(dst + dstoff + (size_t)local * 4) = hv;
}

// ---------------- m97-style GEMM (128x128 tile): C = A(MxK) * Bw(NxK)^T + bias ------
// r8-proven config. mode 0: bf16 headsplit [B,H,S,DK]; mode 3: same *0.125*log2(e)
// (Q pre-scale -> bare v_exp softmax); mode 2: bf16 VhT [B,H,DK,S] (8B stores).
__device__ __forceinline__ void gemm_bt_body(
    const bf16* __restrict__ A, const bf16* __restrict__ Bw,
    const float* __restrict__ bias, bf16* __restrict__ outh,
    int bm, int bn, int mode)
{
  __shared__ alignas(16) bf16 As[128 * 32];
  __shared__ alignas(16) bf16 Bs[128 * 32];
  const int tid = threadIdx.x;
  const int wave = tid >> 6, lane = tid & 63;
  const int quad = lane >> 4, l15 = lane & 15;
  const int wm = (wave >> 1) * 64, wn = (wave & 1) * 64;
  const int lrow = lane >> 2, lcol = (lane & 3) * 8;

  v4f acc[4][4];
#pragma unroll
  for (int i = 0; i < 4; i++)
#pragma unroll
    for (int j = 0; j < 4; j++) { v4f z = {0.f, 0.f, 0.f, 0.f}; acc[i][j] = z; }

  const bf16* gA = A  + (size_t)(bm + wave * 32 + lrow) * 1024 + lcol;
  const bf16* gB = Bw + (size_t)(bn + wave * 32 + lrow) * 1024 + lcol;
  bf16* lA0 = &As[(wave * 32) * 32];
  bf16* lA1 = &As[(wave * 32 + 16) * 32];
  bf16* lB0 = &Bs[(wave * 32) * 32];
  bf16* lB1 = &Bs[(wave * 32 + 16) * 32];

  for (int k0 = 0; k0 < 1024; k0 += 32) {
    gld_lds16(gA + k0, lA0);
    gld_lds16(gA + 16 * 1024 + k0, lA1);
    gld_lds16(gB + k0, lB0);
    gld_lds16(gB + 16 * 1024 + k0, lB1);
    __syncthreads();
    v8bf af[4], bfr[4];
#pragma unroll
    for (int i = 0; i < 4; i++)
      af[i] = *(const v8bf*)&As[(wm + i * 16 + l15) * 32 + quad * 8];
#pragma unroll
    for (int j = 0; j < 4; j++)
      bfr[j] = *(const v8bf*)&Bs[(wn + j * 16 + l15) * 32 + quad * 8];
#pragma unroll
    for (int i = 0; i < 4; i++)
#pragma unroll
      for (int j = 0; j < 4; j++)
        acc[i][j] = MFMA16(af[i], bfr[j], acc[i][j]);
    __syncthreads();
  }

#pragma unroll
  for (int i = 0; i < 4; i++) {
    const int m0 = bm + wm + i * 16 + quad * 4;
#pragma unroll
    for (int j = 0; j < 4; j++) {
      const int n = bn + wn + j * 16 + l15;
      const float bv = bias[n];
      if (mode == 2) {
        // VhT[bh][dk][s]: consecutive r -> consecutive s -> 8B vector store
        int b_ = m0 >> 11, s_ = m0 & 2047;
        int h_ = n >> 6,  dk = n & 63;
        v4bf pk;
#pragma unroll
        for (int r = 0; r < 4; r++) pk[r] = (bf16)(acc[i][j][r] + bv);
        *(v4bf*)&outh[((size_t)((b_ * 16 + h_) * 64 + dk)) * 2048 + s_] = pk;
      } else {
        // mode 3: 1/sqrt(DK) * log2(e) so attn softmax is a bare v_exp
        const float sc = (mode == 3) ? 0.18033688011112042f : 1.0f;
        int h_ = n >> 6,  dk = n & 63;
#pragma unroll
        for (int r = 0; r < 4; r++) {
          int m = m0 + r;
          int b_ = m >> 11, s_ = m & 2047;
          outh[(((size_t)(b_ * 16 + h_) * 2048 + s_) << 6) + dk] =
              (bf16)((acc[i][j][r] + bv) * sc);
        }
      }
    }
  }
}

__global__ __launch_bounds__(256, 2) void gemm_proj_kernel(
    const bf16* qb, const bf16* kb, const bf16* vb,
    const bf16* wqb, const bf16* wkb, const bf16* wvb,
    const float* bq, const float* bk, const float* bv,
    bf16* Qh, bf16* Kh, bf16* VhT)
{
  const bf16* A; const bf16* W; const float* bias; bf16* out; int mode;
  if (blockIdx.z == 0)      { A = qb; W = wqb; bias = bq; out = Qh;  mode = 3; }
  else if (blockIdx.z == 1) { A = kb; W = wkb; bias = bk; out = Kh;  mode = 0; }
  else                      { A = vb; W = wvb; bias = bv; out = VhT; mode = 2; }
  gemm_bt_body(A, W, bias, out, blockIdx.y * 128, blockIdx.x * 128, mode);
}

// ---------------- final GEMM, 64x128 tile: 512 blocks = 2/CU (round-8 win) ----------
__global__ __launch_bounds__(256, 4) void gemm_final_kernel(
    const bf16* __restrict__ Ob, const bf16* __restrict__ wob,
    const float* __restrict__ bo, float* __restrict__ out)
{
  __shared__ alignas(16) bf16 As[64 * 32];
  __shared__ alignas(16) bf16 Bs[128 * 32];
  const int bm = blockIdx.y * 64, bn = blockIdx.x * 128;
  const int tid = threadIdx.x;
  const int wave = tid >> 6, lane = tid & 63;
  const int quad = lane >> 4, l15 = lane & 15;
  const int wm = (wave >> 1) * 32, wn = (wave & 1) * 64;
  const int lrow = lane >> 2, lcol = (lane & 3) * 8;

  v4f acc[2][4];
#pragma unroll
  for (int i = 0; i < 2; i++)
#pragma unroll
    for (int j = 0; j < 4; j++) { v4f z = {0.f, 0.f, 0.f, 0.f}; acc[i][j] = z; }

  const bf16* gA = Ob  + (size_t)(bm + wave * 16 + lrow) * 1024 + lcol;
  const bf16* gB = wob + (size_t)(bn + wave * 32 + lrow) * 1024 + lcol;
  bf16* lA  = &As[(wave * 16) * 32];
  bf16* lB0 = &Bs[(wave * 32) * 32];
  bf16* lB1 = &Bs[(wave * 32 + 16) * 32];

  for (int k0 = 0; k0 < 1024; k0 += 32) {
    gld_lds16(gA + k0, lA);
    gld_lds16(gB + k0, lB0);
    gld_lds16(gB + 16 * 1024 + k0, lB1);
    __syncthreads();
    v8bf af[2], bfr[4];
#pragma unroll
    for (int i = 0; i < 2; i++)
      af[i] = *(const v8bf*)&As[(wm + i * 16 + l15) * 32 + quad * 8];
#pragma unroll
    for (int j = 0; j < 4; j++)
      bfr[j] = *(const v8bf*)&Bs[(wn + j * 16 + l15) * 32 + quad * 8];
#pragma unroll
    for (int i = 0; i < 2; i++)
#pragma unroll
      for (int j = 0; j < 4; j++)
        acc[i][j] = MFMA16(af[i], bfr[j], acc[i][j]);
    __syncthreads();
  }

#pragma unroll
  for (int i = 0; i < 2; i++) {
    const int m0 = bm + wm + i * 16 + quad * 4;
#pragma unroll
    for (int j = 0; j < 4; j++) {
      const int n = bn + wn + j * 16 + l15;
      const float bv = bo[n];
#pragma unroll
      for (int r = 0; r < 4; r++)
        out[(size_t)(m0 + r) * 1024 + n] = acc[i][j][r] + bv;
    }
  }
}

// ---------------- flash attention v10b: r14 key-split body, (128,2) bounds ----------
// r14 PASSED correctness (absmax 0.015625) but spilled because launch_bounds(128,3)
// shrank the allocator target to 84 VGPR (allocator pads min-waves ~2x: (128,2)->128,
// (128)->164, (128,3)->84, (256,4)->64 across r3/r12/r13/r14). With (128,2) this
// body compiles to ~128 VGPR (r13-verified) -> 4 waves/SIMD resource-feasible ->
// the 1536-block grid gives 6 blocks/CU = 3 waves/SIMD co-resident naturally.
// Decomposition (lockstep wave-pairs ALWAYS -- r10 lesson):
//   slot  0..15 (A): full tiles t=0..15, qt=2t+wave, chunks 0..t, direct store.
//   slot 16..31 (B): LOWER halves of long tiles t=16..31: chunks 0..15 -> partials.
//   slot 32..47 (C): DIAG halves: chunks 16..t -> partials.
// CU class balance: 66 chunk-units each; max chain 17 (was 32). Partials additive
// (no running max): bf16 O + fp32 lsum, combined by attn_combine_kernel.
// Transposed-QK softmax (r13 win), diag peel, bare v_exp.
__global__ __launch_bounds__(128, 2) void attn_kernel(
    const bf16* __restrict__ Qh, const bf16* __restrict__ Kh,
    const bf16* __restrict__ VhT, bf16* __restrict__ Ob,
    bf16* __restrict__ po, float* __restrict__ plsum)
{
  __shared__ alignas(16) bf16 Ps[2][32 * 72];   // per-wave P slice [q=32][k=64 pad 72]
  const int tid = threadIdx.x;
  const int wave = tid >> 6, lane = tid & 63;
  const int quad = lane >> 4, l15 = lane & 15;
  const int bh = blockIdx.x, slot = blockIdx.y;
  const int b = bh >> 4, h = bh & 15;

  int t, lo, part;                    // part: -1 direct, 0 lower half, 1 diag half
  if (slot < 16) {
    t = (slot < 8) ? slot : 23 - slot;            // t in 0..15
    lo = 0; part = -1;
  } else if (slot < 32) {
    int c = slot - 16;
    t = 16 + ((c < 8) ? c : 23 - c);              // t in 16..31
    lo = 0; part = 0;
  } else {
    int c = slot - 32;
    t = 16 + ((c < 8) ? c : 23 - c);
    lo = 16; part = 1;
  }
  const int qt = 2 * t + wave;        // both waves: same chunk range (lockstep)
  const int L = t;                    // global diagonal chunk index
  const int hi = (part == 0) ? 15 : t;

  const bf16* Qb = Qh + (size_t)bh * Sq * 64;
  const bf16* Kb = Kh + (size_t)bh * Sq * 64;
  const bf16* Vb = VhT + (size_t)bh * 64 * Sq;
  bf16* Pw = &Ps[wave][0];
  const int r0 = qt * 32;

  // Q fragments (pre-scaled in projection): [q=l15 row][dk=ks*32+quad*8+j]
  v8bf aq[2][2];
#pragma unroll
  for (int s = 0; s < 2; s++)
#pragma unroll
    for (int ks = 0; ks < 2; ks++)
      aq[s][ks] = *(const v8bf*)&Qb[(size_t)(r0 + s * 16 + l15) * 64 + ks * 32 + quad * 8];

  float lsumT[2];                // per-lane running sum for q-row = l15 (s halves)
  v4f o[2][4];
  lsumT[0] = 0.f; lsumT[1] = 0.f;
#pragma unroll
  for (int s = 0; s < 2; s++)
#pragma unroll
    for (int j = 0; j < 4; j++) { v4f z = {0.f, 0.f, 0.f, 0.f}; o[s][j] = z; }

  auto loadK = [&](int kb, v8bf (&BK)[4][2]) {
#pragma unroll
    for (int n = 0; n < 4; n++) {
      BK[n][0] = *(const v8bf*)&Kb[(size_t)(kb + n * 16 + l15) * 64 + quad * 8];
      BK[n][1] = *(const v8bf*)&Kb[(size_t)(kb + n * 16 + l15) * 64 + 32 + quad * 8];
    }
  };
  auto loadV = [&](int kb, v8bf (&BV)[4][2]) {
#pragma unroll
    for (int n = 0; n < 4; n++) {
      BV[n][0] = *(const v8bf*)&Vb[(size_t)(n * 16 + l15) * 2048 + kb + quad * 8];
      BV[n][1] = *(const v8bf*)&Vb[(size_t)(n * 16 + l15) * 2048 + kb + 32 + quad * 8];
    }
  };
  // transposed QK: S^T[k=n*16+quad*4+r][q=l15]; P written as 8B rows, PV reads b128
  auto compute = [&](const v8bf (&BK)[4][2], const v8bf (&BV)[4][2], int kc, bool diag) {
    const int kbase = kc * 64;
#pragma unroll
    for (int s = 0; s < 2; s++) {
      v4f cnT[4];
#pragma unroll
      for (int n = 0; n < 4; n++) {
        v4f z = {0.f, 0.f, 0.f, 0.f};
        cnT[n] = MFMA16(BK[n][0], aq[s][0], z);
        cnT[n] = MFMA16(BK[n][1], aq[s][1], cnT[n]);
      }
      const int qglob = r0 + s * 16 + l15;        // this lane's q-row
#pragma unroll
      for (int n = 0; n < 4; n++) {
        const int kb_n = kbase + n * 16 + quad * 4;
        v4bf pk;
#pragma unroll
        for (int r = 0; r < 4; r++) {
          float e = exp2_raw(cnT[n][r]);
          if (diag && (kb_n + r) > qglob) e = 0.f;
          lsumT[s] += e;
          pk[r] = (bf16)e;
        }
        *(v4bf*)&Pw[(s * 16 + l15) * 72 + n * 16 + quad * 4] = pk;
      }
    }
#pragma unroll
    for (int s = 0; s < 2; s++) {
      v8bf ap0 = *(const v8bf*)&Pw[(s * 16 + l15) * 72 + quad * 8];
      v8bf ap1 = *(const v8bf*)&Pw[(s * 16 + l15) * 72 + 32 + quad * 8];
#pragma unroll
      for (int j = 0; j < 4; j++) {
        o[s][j] = MFMA16(ap0, BV[j][0], o[s][j]);
        o[s][j] = MFMA16(ap1, BV[j][1], o[s][j]);
      }
    }
  };

  {
    v8bf bk0[4][2], bk1[4][2], bvv[4][2];
    loadK(lo * 64, bk0);
    int kc = lo;
    while (kc < hi) {
      loadV(kc * 64, bvv);
      loadK((kc + 1) * 64, bk1);
      compute(bk0, bvv, kc, false);
      ++kc;
      if (kc >= hi) {              // final chunk of range is in bk1
        loadV(kc * 64, bvv);
        compute(bk1, bvv, kc, kc == L);
        kc = -1;
        break;
      }
      loadV(kc * 64, bvv);
      loadK((kc + 1) * 64, bk0);
      compute(bk1, bvv, kc, false);
      ++kc;
    }
    if (kc >= 0) {                 // single-chunk range or final in bk0
      loadV(kc * 64, bvv);
      compute(bk0, bvv, kc, kc == L);
    }
  }

  // lsumT: reduce across the 4 quad-lanes sharing each l15 (xor 16, 32)
#pragma unroll
  for (int s = 0; s < 2; s++) {
    lsumT[s] += __shfl_xor(lsumT[s], 16, 64);
    lsumT[s] += __shfl_xor(lsumT[s], 32, 64);
  }

  if (part < 0) {
    // direct: redistribute inv to o's row pattern, normalize, store
#pragma unroll
    for (int s = 0; s < 2; s++) {
      float inv[4];
#pragma unroll
      for (int r = 0; r < 4; r++)
        inv[r] = 1.0f / __shfl(lsumT[s], quad * 4 + r, 64);
#pragma unroll
      for (int r = 0; r < 4; r++) {
        const int sg = r0 + s * 16 + quad * 4 + r;
#pragma unroll
        for (int j = 0; j < 4; j++)
          Ob[((size_t)(b * Sq + sg)) * 1024 + h * 64 + j * 16 + l15] =
              (bf16)(o[s][j][r] * inv[r]);
      }
    }
  } else {
    // partial: unnormalized bf16 O + fp32 lsum to workspace (additive halves)
    const size_t pidx = ((size_t)(bh * 32 + (qt - 32)) * 2 + part);
    bf16* pob = po + pidx * 2048;             // [32 rows][64 cols]
#pragma unroll
    for (int s = 0; s < 2; s++)
#pragma unroll
      for (int j = 0; j < 4; j++)
#pragma unroll
        for (int r = 0; r < 4; r++)
          pob[(s * 16 + quad * 4 + r) * 64 + j * 16 + l15] = (bf16)o[s][j][r];
    if (quad == 0) {
#pragma unroll
      for (int s = 0; s < 2; s++)
        plsum[pidx * 32 + s * 16 + l15] = lsumT[s];
    }
  }
}

// ---------------- combine split-tile partials: Ob = (o0+o1)/(l0+l1) ----------------
__global__ __launch_bounds__(256) void attn_combine_kernel(
    const bf16* __restrict__ po, const float* __restrict__ plsum,
    bf16* __restrict__ Ob)
{
  const int bh = blockIdx.x, ti = blockIdx.y;      // ti: tile qt = 32 + ti
  const int b = bh >> 4, h = bh & 15;
  const int tid = threadIdx.x;
  const int col = tid & 63, rg = tid >> 6;         // rg 0..3 -> rows rg*8..rg*8+7
  const size_t pidx = (size_t)(bh * 32 + ti) * 2;
  const bf16* p0 = po + pidx * 2048;
  const bf16* p1 = p0 + 2048;
  const float* l0 = plsum + pidx * 32;
#pragma unroll
  for (int rr = 0; rr < 8; rr++) {
    const int row = rg * 8 + rr;
    const float inv = 1.0f / (l0[row] + l0[32 + row]);
    const float v = (float)p0[row * 64 + col] + (float)p1[row * 64 + col];
    const int sg = (32 + ti) * 32 + row;
    Ob[((size_t)(b * 2048 + sg)) * 1024 + h * 64 + col] = (bf16)(v * inv);
  }
}

// ---------------- launch ----------------
extern "C" void kernel_launch(void* const* d_in, const int* in_sizes, int n_in,
                              void* d_out, int out_size, void* d_ws, size_t ws_size,
                              hipStream_t stream) {
  (void)in_sizes; (void)n_in; (void)out_size; (void)ws_size;
  const float* kin = (const float*)d_in[0];
  const float* qin = (const float*)d_in[1];
  const float* vin = (const float*)d_in[2];
  const float* wq  = (const float*)d_in[3];
  const float* bq  = (const float*)d_in[4];
  const float* wk  = (const float*)d_in[5];
  const float* bk  = (const float*)d_in[6];
  const float* wv  = (const float*)d_in[7];
  const float* bv  = (const float*)d_in[8];
  const float* wo  = (const float*)d_in[9];
  const float* bo  = (const float*)d_in[10];

  bf16* ws = (bf16*)d_ws;
  bf16* qb  = ws;
  bf16* kb  = ws + NI;
  bf16* vb  = ws + 2 * NI;
  bf16* wqb = ws + 3 * NI;
  bf16* wkb = wqb + NW;
  bf16* wvb = wqb + 2 * NW;
  bf16* wob = wqb + 3 * NW;
  bf16* Qh  = ws + 3 * NI + 4 * NW;
  bf16* Kh  = Qh + NI;
  bf16* VhT = Qh + 2 * NI;
  bf16* Ob  = Qh + 3 * NI;
  // bf16 partials after Ob: 32bh x 32tiles x 2 parts x (32x64) = 8 MB; lsum 256 KB
  bf16*  po    = Ob + NI;
  float* plsum = (float*)(po + (size_t)32 * 32 * 2 * 2048);

  convert_kernel<<<16384, 256, 0, stream>>>(qin, kin, vin, wq, wk, wv, wo, ws);
  gemm_proj_kernel<<<dim3(8, 32, 3), 256, 0, stream>>>(
      qb, kb, vb, wqb, wkb, wvb, bq, bk, bv, Qh, Kh, VhT);
  attn_kernel<<<dim3(32, 48), 128, 0, stream>>>(Qh, Kh, VhT, Ob, po, plsum);
  attn_combine_kernel<<<dim3(32, 32), 256, 0, stream>>>(po, plsum, Ob);
  gemm_final_kernel<<<dim3(8, 64), 256, 0, stream>>>(Ob, wob, bo, (float*)d_out);
}

// Round 17
// 252.820 us; speedup vs baseline: 1.0509x; 1.0509x over previous
//
#include <hip/hip_runtime.h>

typedef __bf16 bf16;
typedef __bf16 v8bf __attribute__((ext_vector_type(8)));
typedef __bf16 v4bf __attribute__((ext_vector_type(4)));
typedef float  v4f  __attribute__((ext_vector_type(4)));

#define MFMA16(a,b,c) __builtin_amdgcn_mfma_f32_16x16x32_bf16((a),(b),(c),0,0,0)

// B=2, S=2048, D=1024, H=16, DK=64
static constexpr int Sq = 2048;
static constexpr size_t NI = 4194304;  // B*S*D
static constexpr size_t NW = 1048576;  // D*D

__device__ __forceinline__ void gld_lds16(const void* g, void* l) {
  __builtin_amdgcn_global_load_lds(
      (__attribute__((address_space(1))) unsigned int*)g,
      (__attribute__((address_space(3))) unsigned int*)l,
      16, 0, 0);
}

// bare v_exp_f32 (2^x) via compiler intrinsic: no libm guards, hazard handled.
__device__ __forceinline__ float exp2_raw(float x) {
  return __builtin_amdgcn_exp2f(x);
}

// ---------------- convert fp32 -> bf16 (q,k,v,wq,wk,wv,wo) ----------------
// v2: 8 elems/thread (2x float4 loads, 1x 16B v8bf store), grid-stride at 2048
// blocks (G11/G13): was 16384 blocks x 4 elems with 8B stores.
__global__ __launch_bounds__(256) void convert_kernel(
    const float* __restrict__ q, const float* __restrict__ k, const float* __restrict__ v,
    const float* __restrict__ wq, const float* __restrict__ wk,
    const float* __restrict__ wv, const float* __restrict__ wo,
    bf16* __restrict__ dst)
{
  const int NI8 = 524288;   // NI/8 = 2^19
  const int NW8 = 131072;   // NW/8 = 2^17
  const int total8 = 3 * NI8 + 4 * NW8;   // 2097152
  for (int g = blockIdx.x * 256 + threadIdx.x; g < total8; g += gridDim.x * 256) {
    const float* src; size_t dstoff; int local;
    if (g < 3 * NI8) {
      int a = g >> 19; local = g & (NI8 - 1);
      src = (a == 0) ? q : ((a == 1) ? k : v);
      dstoff = (size_t)a * NI;
    } else {
      int t = g - 3 * NI8;
      int a = t >> 17; local = t & (NW8 - 1);
      src = (a == 0) ? wq : ((a == 1) ? wk : ((a == 2) ? wv : wo));
      dstoff = 3 * NI + (size_t)a * NW;
    }
    float4 f0 = ((const float4*)src)[local * 2];
    float4 f1 = ((const float4*)src)[local * 2 + 1];
    v8bf hv = { (bf16)f0.x, (bf16)f0.y, (bf16)f0.z, (bf16)f0.w,
                (bf16)f1.x, (bf16)f1.y, (bf16)f1.z, (bf16)f1.w };
    *(v8bf*)(dst + dstoff + (size_t)local * 8) = hv;
  }
}

// ---------------- m97-style GEMM (128x128 tile): C = A(MxK) * Bw(NxK)^T + bias ------
// r8-proven config. mode 0: bf16 headsplit [B,H,S,DK]; mode 3: same *0.125*log2(e)
// (Q pre-scale -> bare v_exp softmax); mode 2: bf16 VhT [B,H,DK,S] (8B stores).
__device__ __forceinline__ void gemm_bt_body(
    const bf16* __restrict__ A, const bf16* __restrict__ Bw,
    const float* __restrict__ bias, bf16* __restrict__ outh,
    int bm, int bn, int mode)
{
  __shared__ alignas(16) bf16 As[128 * 32];
  __shared__ alignas(16) bf16 Bs[128 * 32];
  const int tid = threadIdx.x;
  const int wave = tid >> 6, lane = tid & 63;
  const int quad = lane >> 4, l15 = lane & 15;
  const int wm = (wave >> 1) * 64, wn = (wave & 1) * 64;
  const int lrow = lane >> 2, lcol = (lane & 3) * 8;

  v4f acc[4][4];
#pragma unroll
  for (int i = 0; i < 4; i++)
#pragma unroll
    for (int j = 0; j < 4; j++) { v4f z = {0.f, 0.f, 0.f, 0.f}; acc[i][j] = z; }

  const bf16* gA = A  + (size_t)(bm + wave * 32 + lrow) * 1024 + lcol;
  const bf16* gB = Bw + (size_t)(bn + wave * 32 + lrow) * 1024 + lcol;
  bf16* lA0 = &As[(wave * 32) * 32];
  bf16* lA1 = &As[(wave * 32 + 16) * 32];
  bf16* lB0 = &Bs[(wave * 32) * 32];
  bf16* lB1 = &Bs[(wave * 32 + 16) * 32];

  for (int k0 = 0; k0 < 1024; k0 += 32) {
    gld_lds16(gA + k0, lA0);
    gld_lds16(gA + 16 * 1024 + k0, lA1);
    gld_lds16(gB + k0, lB0);
    gld_lds16(gB + 16 * 1024 + k0, lB1);
    __syncthreads();
    v8bf af[4], bfr[4];
#pragma unroll
    for (int i = 0; i < 4; i++)
      af[i] = *(const v8bf*)&As[(wm + i * 16 + l15) * 32 + quad * 8];
#pragma unroll
    for (int j = 0; j < 4; j++)
      bfr[j] = *(const v8bf*)&Bs[(wn + j * 16 + l15) * 32 + quad * 8];
#pragma unroll
    for (int i = 0; i < 4; i++)
#pragma unroll
      for (int j = 0; j < 4; j++)
        acc[i][j] = MFMA16(af[i], bfr[j], acc[i][j]);
    __syncthreads();
  }

#pragma unroll
  for (int i = 0; i < 4; i++) {
    const int m0 = bm + wm + i * 16 + quad * 4;
#pragma unroll
    for (int j = 0; j < 4; j++) {
      const int n = bn + wn + j * 16 + l15;
      const float bv = bias[n];
      if (mode == 2) {
        // VhT[bh][dk][s]: consecutive r -> consecutive s -> 8B vector store
        int b_ = m0 >> 11, s_ = m0 & 2047;
        int h_ = n >> 6,  dk = n & 63;
        v4bf pk;
#pragma unroll
        for (int r = 0; r < 4; r++) pk[r] = (bf16)(acc[i][j][r] + bv);
        *(v4bf*)&outh[((size_t)((b_ * 16 + h_) * 64 + dk)) * 2048 + s_] = pk;
      } else {
        // mode 3: 1/sqrt(DK) * log2(e) so attn softmax is a bare v_exp
        const float sc = (mode == 3) ? 0.18033688011112042f : 1.0f;
        int h_ = n >> 6,  dk = n & 63;
#pragma unroll
        for (int r = 0; r < 4; r++) {
          int m = m0 + r;
          int b_ = m >> 11, s_ = m & 2047;
          outh[(((size_t)(b_ * 16 + h_) * 2048 + s_) << 6) + dk] =
              (bf16)((acc[i][j][r] + bv) * sc);
        }
      }
    }
  }
}

__global__ __launch_bounds__(256, 2) void gemm_proj_kernel(
    const bf16* qb, const bf16* kb, const bf16* vb,
    const bf16* wqb, const bf16* wkb, const bf16* wvb,
    const float* bq, const float* bk, const float* bv,
    bf16* Qh, bf16* Kh, bf16* VhT)
{
  const bf16* A; const bf16* W; const float* bias; bf16* out; int mode;
  if (blockIdx.z == 0)      { A = qb; W = wqb; bias = bq; out = Qh;  mode = 3; }
  else if (blockIdx.z == 1) { A = kb; W = wkb; bias = bk; out = Kh;  mode = 0; }
  else                      { A = vb; W = wvb; bias = bv; out = VhT; mode = 2; }
  gemm_bt_body(A, W, bias, out, blockIdx.y * 128, blockIdx.x * 128, mode);
}

// ---------------- final GEMM, 64x128 tile: 512 blocks = 2/CU (round-8 win) ----------
__global__ __launch_bounds__(256, 4) void gemm_final_kernel(
    const bf16* __restrict__ Ob, const bf16* __restrict__ wob,
    const float* __restrict__ bo, float* __restrict__ out)
{
  __shared__ alignas(16) bf16 As[64 * 32];
  __shared__ alignas(16) bf16 Bs[128 * 32];
  const int bm = blockIdx.y * 64, bn = blockIdx.x * 128;
  const int tid = threadIdx.x;
  const int wave = tid >> 6, lane = tid & 63;
  const int quad = lane >> 4, l15 = lane & 15;
  const int wm = (wave >> 1) * 32, wn = (wave & 1) * 64;
  const int lrow = lane >> 2, lcol = (lane & 3) * 8;

  v4f acc[2][4];
#pragma unroll
  for (int i = 0; i < 2; i++)
#pragma unroll
    for (int j = 0; j < 4; j++) { v4f z = {0.f, 0.f, 0.f, 0.f}; acc[i][j] = z; }

  const bf16* gA = Ob  + (size_t)(bm + wave * 16 + lrow) * 1024 + lcol;
  const bf16* gB = wob + (size_t)(bn + wave * 32 + lrow) * 1024 + lcol;
  bf16* lA  = &As[(wave * 16) * 32];
  bf16* lB0 = &Bs[(wave * 32) * 32];
  bf16* lB1 = &Bs[(wave * 32 + 16) * 32];

  for (int k0 = 0; k0 < 1024; k0 += 32) {
    gld_lds16(gA + k0, lA);
    gld_lds16(gB + k0, lB0);
    gld_lds16(gB + 16 * 1024 + k0, lB1);
    __syncthreads();
    v8bf af[2], bfr[4];
#pragma unroll
    for (int i = 0; i < 2; i++)
      af[i] = *(const v8bf*)&As[(wm + i * 16 + l15) * 32 + quad * 8];
#pragma unroll
    for (int j = 0; j < 4; j++)
      bfr[j] = *(const v8bf*)&Bs[(wn + j * 16 + l15) * 32 + quad * 8];
#pragma unroll
    for (int i = 0; i < 2; i++)
#pragma unroll
      for (int j = 0; j < 4; j++)
        acc[i][j] = MFMA16(af[i], bfr[j], acc[i][j]);
    __syncthreads();
  }

#pragma unroll
  for (int i = 0; i < 2; i++) {
    const int m0 = bm + wm + i * 16 + quad * 4;
#pragma unroll
    for (int j = 0; j < 4; j++) {
      const int n = bn + wn + j * 16 + l15;
      const float bv = bo[n];
#pragma unroll
      for (int r = 0; r < 4; r++)
        out[(size_t)(m0 + r) * 1024 + n] = acc[i][j][r] + bv;
    }
  }
}

// ---------------- flash attention v9 (r15-proven, 70.4 us) ----------------
// Block = 2 waves on tiles (2u, 2u+1), lockstep chunk range 0..u (L1 K/V sharing).
// Closed lines (measured): key-split decomposition (r0/r10/r14/r16 -- all regress
// even with clean resources); V double-buffer (r12: latency already covered);
// >2 waves/SIMD of this body (r3/r7/r14: allocator pads min-waves ~2x -> spill).
// gy->u permutation balances each CU class at 66 chunk-units. No running max
// (scores bounded); Q pre-scaled by 0.125*log2e -> softmax is bare v_exp_f32.
// Transposed QK (r13 win): cnT = mfma(K,Q) -> S^T[k@quad*4+r][q@l15] -> P stores
// are 8 x ds_write_b64/chunk; PV reads row-major b128. Diagonal peeled.
// setprio kept (r15: neutral, free).
__global__ __launch_bounds__(128, 2) void attn_kernel(
    const bf16* __restrict__ Qh, const bf16* __restrict__ Kh,
    const bf16* __restrict__ VhT, bf16* __restrict__ Ob)
{
  __shared__ alignas(16) bf16 Ps[2][32 * 72];   // per-wave P slice [q=32][k=64 pad 72]
  const int tid = threadIdx.x;
  const int wave = tid >> 6, lane = tid & 63;
  const int quad = lane >> 4, l15 = lane & 15;
  const int bh = blockIdx.x, gy = blockIdx.y;
  const int b = bh >> 4, h = bh & 15;
  const int r8 = gy & 7, q8 = gy >> 3;
  const int u = 8 * q8 + ((q8 & 1) ? (7 - r8) : r8);
  const int qt = 2 * u + wave;                  // both waves: chunks 0..u
  const int L = u;
  const bf16* Qb = Qh + (size_t)bh * Sq * 64;
  const bf16* Kb = Kh + (size_t)bh * Sq * 64;
  const bf16* Vb = VhT + (size_t)bh * 64 * Sq;
  bf16* Pw = &Ps[wave][0];
  const int r0 = qt * 32;

  // Q fragments (pre-scaled in projection): [q=l15 row][dk=ks*32+quad*8+j]
  v8bf aq[2][2];
#pragma unroll
  for (int s = 0; s < 2; s++)
#pragma unroll
    for (int ks = 0; ks < 2; ks++)
      aq[s][ks] = *(const v8bf*)&Qb[(size_t)(r0 + s * 16 + l15) * 64 + ks * 32 + quad * 8];

  float lsumT[2];                // per-lane running sum for q-row = l15 (s halves)
  v4f o[2][4];
  lsumT[0] = 0.f; lsumT[1] = 0.f;
#pragma unroll
  for (int s = 0; s < 2; s++)
#pragma unroll
    for (int j = 0; j < 4; j++) { v4f z = {0.f, 0.f, 0.f, 0.f}; o[s][j] = z; }

  auto loadK = [&](int kb, v8bf (&BK)[4][2]) {
#pragma unroll
    for (int n = 0; n < 4; n++) {
      BK[n][0] = *(const v8bf*)&Kb[(size_t)(kb + n * 16 + l15) * 64 + quad * 8];
      BK[n][1] = *(const v8bf*)&Kb[(size_t)(kb + n * 16 + l15) * 64 + 32 + quad * 8];
    }
  };
  auto loadV = [&](int kb, v8bf (&BV)[4][2]) {
#pragma unroll
    for (int n = 0; n < 4; n++) {
      BV[n][0] = *(const v8bf*)&Vb[(size_t)(n * 16 + l15) * 2048 + kb + quad * 8];
      BV[n][1] = *(const v8bf*)&Vb[(size_t)(n * 16 + l15) * 2048 + kb + 32 + quad * 8];
    }
  };
  // diag is always a call-site literal -> constant-folded after inlining
  auto compute = [&](const v8bf (&BK)[4][2], const v8bf (&BV)[4][2], int kc, bool diag) {
    const int kbase = kc * 64;
#pragma unroll
    for (int s = 0; s < 2; s++) {
      // transposed QK: S^T[k = n*16+quad*4+r][q = l15]
      v4f cnT[4];
      __builtin_amdgcn_s_setprio(1);
#pragma unroll
      for (int n = 0; n < 4; n++) {
        v4f z = {0.f, 0.f, 0.f, 0.f};
        cnT[n] = MFMA16(BK[n][0], aq[s][0], z);
        cnT[n] = MFMA16(BK[n][1], aq[s][1], cnT[n]);
      }
      __builtin_amdgcn_s_setprio(0);
      const int qglob = r0 + s * 16 + l15;        // this lane's q-row
#pragma unroll
      for (int n = 0; n < 4; n++) {
        const int kb_n = kbase + n * 16 + quad * 4;
        v4bf pk;
#pragma unroll
        for (int r = 0; r < 4; r++) {
          float e = exp2_raw(cnT[n][r]);
          if (diag && (kb_n + r) > qglob) e = 0.f;
          lsumT[s] += e;
          pk[r] = (bf16)e;
        }
        // P[q=s*16+l15][k = n*16+quad*4 .. +3] -> single 8B vector write
        *(v4bf*)&Pw[(s * 16 + l15) * 72 + n * 16 + quad * 4] = pk;
      }
    }
    // PV: A-layout read of own wave's P (row-major [q][k], matches write layout)
#pragma unroll
    for (int s = 0; s < 2; s++) {
      v8bf ap0 = *(const v8bf*)&Pw[(s * 16 + l15) * 72 + quad * 8];
      v8bf ap1 = *(const v8bf*)&Pw[(s * 16 + l15) * 72 + 32 + quad * 8];
      __builtin_amdgcn_s_setprio(1);
#pragma unroll
      for (int j = 0; j < 4; j++) {
        o[s][j] = MFMA16(ap0, BV[j][0], o[s][j]);
        o[s][j] = MFMA16(ap1, BV[j][1], o[s][j]);
      }
      __builtin_amdgcn_s_setprio(0);
    }
  };

  v8bf bk0[4][2], bk1[4][2], bvv[4][2];
  loadK(0, bk0);
  int kc = 0;
  // main loop: non-diagonal chunks only (no mask code)
  while (kc < L) {
    loadV(kc * 64, bvv);
    loadK((kc + 1) * 64, bk1);
    compute(bk0, bvv, kc, false);
    ++kc;
    if (kc >= L) {                 // diagonal chunk is in bk1
      loadV(kc * 64, bvv);
      compute(bk1, bvv, kc, true);
      kc = -1;
      break;
    }
    loadV(kc * 64, bvv);
    loadK((kc + 1) * 64, bk0);
    compute(bk1, bvv, kc, false);
    ++kc;
  }
  if (kc >= 0) {                   // exited with diagonal chunk in bk0 (incl. L==0)
    loadV(kc * 64, bvv);
    compute(bk0, bvv, kc, true);
  }

  // epilogue: lsumT reduce across the 4 quad-lanes sharing each l15 (xor 16, 32),
  // then redistribute to o's row pattern (row q = quad*4+r held at lane l15=q).
#pragma unroll
  for (int s = 0; s < 2; s++) {
    lsumT[s] += __shfl_xor(lsumT[s], 16, 64);
    lsumT[s] += __shfl_xor(lsumT[s], 32, 64);
  }
#pragma unroll
  for (int s = 0; s < 2; s++) {
    float inv[4];
#pragma unroll
    for (int r = 0; r < 4; r++)
      inv[r] = 1.0f / __shfl(lsumT[s], quad * 4 + r, 64);
#pragma unroll
    for (int r = 0; r < 4; r++) {
      const int sg = r0 + s * 16 + quad * 4 + r;
#pragma unroll
      for (int j = 0; j < 4; j++)
        Ob[((size_t)(b * Sq + sg)) * 1024 + h * 64 + j * 16 + l15] =
            (bf16)(o[s][j][r] * inv[r]);
    }
  }
}

// ---------------- launch ----------------
extern "C" void kernel_launch(void* const* d_in, const int* in_sizes, int n_in,
                              void* d_out, int out_size, void* d_ws, size_t ws_size,
                              hipStream_t stream) {
  (void)in_sizes; (void)n_in; (void)out_size; (void)ws_size;
  const float* kin = (const float*)d_in[0];
  const float* qin = (const float*)d_in[1];
  const float* vin = (const float*)d_in[2];
  const float* wq  = (const float*)d_in[3];
  const float* bq  = (const float*)d_in[4];
  const float* wk  = (const float*)d_in[5];
  const float* bk  = (const float*)d_in[6];
  const float* wv  = (const float*)d_in[7];
  const float* bv  = (const float*)d_in[8];
  const float* wo  = (const float*)d_in[9];
  const float* bo  = (const float*)d_in[10];

  bf16* ws = (bf16*)d_ws;
  bf16* qb  = ws;
  bf16* kb  = ws + NI;
  bf16* vb  = ws + 2 * NI;
  bf16* wqb = ws + 3 * NI;
  bf16* wkb = wqb + NW;
  bf16* wvb = wqb + 2 * NW;
  bf16* wob = wqb + 3 * NW;
  bf16* Qh  = ws + 3 * NI + 4 * NW;
  bf16* Kh  = Qh + NI;
  bf16* VhT = Qh + 2 * NI;
  bf16* Ob  = Qh + 3 * NI;

  convert_kernel<<<2048, 256, 0, stream>>>(qin, kin, vin, wq, wk, wv, wo, ws);
  gemm_proj_kernel<<<dim3(8, 32, 3), 256, 0, stream>>>(
      qb, kb, vb, wqb, wkb, wvb, bq, bk, bv, Qh, Kh, VhT);
  attn_kernel<<<dim3(32, 32), 128, 0, stream>>>(Qh, Kh, VhT, Ob);
  gemm_final_kernel<<<dim3(8, 64), 256, 0, stream>>>(Ob, wob, bo, (float*)d_out);
}

// Round 18
// 249.447 us; speedup vs baseline: 1.0651x; 1.0135x over previous
//
#include <hip/hip_runtime.h>

typedef __bf16 bf16;
typedef __bf16 v8bf __attribute__((ext_vector_type(8)));
typedef __bf16 v4bf __attribute__((ext_vector_type(4)));
typedef float  v4f  __attribute__((ext_vector_type(4)));

#define MFMA16(a,b,c) __builtin_amdgcn_mfma_f32_16x16x32_bf16((a),(b),(c),0,0,0)

// B=2, S=2048, D=1024, H=16, DK=64
static constexpr int Sq = 2048;
static constexpr size_t NI = 4194304;  // B*S*D
static constexpr size_t NW = 1048576;  // D*D

__device__ __forceinline__ void gld_lds16(const void* g, void* l) {
  __builtin_amdgcn_global_load_lds(
      (__attribute__((address_space(1))) unsigned int*)g,
      (__attribute__((address_space(3))) unsigned int*)l,
      16, 0, 0);
}

// bare v_exp_f32 (2^x) via compiler intrinsic: no libm guards, hazard handled.
__device__ __forceinline__ float exp2_raw(float x) {
  return __builtin_amdgcn_exp2f(x);
}

// ---------------- convert fp32 -> bf16 (q,k,v,wq,wk,wv,wo) ----------------
// r15 version (16384 blocks x 4 elems): r17's 8-elem grid-stride variant was flat.
__global__ __launch_bounds__(256) void convert_kernel(
    const float* __restrict__ q, const float* __restrict__ k, const float* __restrict__ v,
    const float* __restrict__ wq, const float* __restrict__ wk,
    const float* __restrict__ wv, const float* __restrict__ wo,
    bf16* __restrict__ dst)
{
  const int NI4 = 1048576;  // NI/4 = 2^20
  const int NW4 = 262144;   // NW/4 = 2^18
  int idx = blockIdx.x * 256 + threadIdx.x;   // total 4194304
  const float* src; size_t dstoff; int local;
  if (idx < 3 * NI4) {
    int a = idx >> 20; local = idx & (NI4 - 1);
    src = (a == 0) ? q : ((a == 1) ? k : v);
    dstoff = (size_t)a * NI;
  } else {
    int t = idx - 3 * NI4;
    int a = t >> 18; local = t & (NW4 - 1);
    src = (a == 0) ? wq : ((a == 1) ? wk : ((a == 2) ? wv : wo));
    dstoff = 3 * NI + (size_t)a * NW;
  }
  float4 f = ((const float4*)src)[local];
  v4bf hv = { (bf16)f.x, (bf16)f.y, (bf16)f.z, (bf16)f.w };
  *(v4bf*)(dst + dstoff + (size_t)local * 4) = hv;
}

// ---------------- m97-style GEMM (128x128 tile): C = A(MxK) * Bw(NxK)^T + bias ------
// r8-proven config. mode 0: bf16 headsplit [B,H,S,DK]; mode 3: same *0.125*log2(e)
// (Q pre-scale -> bare v_exp softmax); mode 2: bf16 VhT [B,H,DK,S] (8B stores).
__device__ __forceinline__ void gemm_bt_body(
    const bf16* __restrict__ A, const bf16* __restrict__ Bw,
    const float* __restrict__ bias, bf16* __restrict__ outh,
    int bm, int bn, int mode)
{
  __shared__ alignas(16) bf16 As[128 * 32];
  __shared__ alignas(16) bf16 Bs[128 * 32];
  const int tid = threadIdx.x;
  const int wave = tid >> 6, lane = tid & 63;
  const int quad = lane >> 4, l15 = lane & 15;
  const int wm = (wave >> 1) * 64, wn = (wave & 1) * 64;
  const int lrow = lane >> 2, lcol = (lane & 3) * 8;

  v4f acc[4][4];
#pragma unroll
  for (int i = 0; i < 4; i++)
#pragma unroll
    for (int j = 0; j < 4; j++) { v4f z = {0.f, 0.f, 0.f, 0.f}; acc[i][j] = z; }

  const bf16* gA = A  + (size_t)(bm + wave * 32 + lrow) * 1024 + lcol;
  const bf16* gB = Bw + (size_t)(bn + wave * 32 + lrow) * 1024 + lcol;
  bf16* lA0 = &As[(wave * 32) * 32];
  bf16* lA1 = &As[(wave * 32 + 16) * 32];
  bf16* lB0 = &Bs[(wave * 32) * 32];
  bf16* lB1 = &Bs[(wave * 32 + 16) * 32];

  for (int k0 = 0; k0 < 1024; k0 += 32) {
    gld_lds16(gA + k0, lA0);
    gld_lds16(gA + 16 * 1024 + k0, lA1);
    gld_lds16(gB + k0, lB0);
    gld_lds16(gB + 16 * 1024 + k0, lB1);
    __syncthreads();
    v8bf af[4], bfr[4];
#pragma unroll
    for (int i = 0; i < 4; i++)
      af[i] = *(const v8bf*)&As[(wm + i * 16 + l15) * 32 + quad * 8];
#pragma unroll
    for (int j = 0; j < 4; j++)
      bfr[j] = *(const v8bf*)&Bs[(wn + j * 16 + l15) * 32 + quad * 8];
#pragma unroll
    for (int i = 0; i < 4; i++)
#pragma unroll
      for (int j = 0; j < 4; j++)
        acc[i][j] = MFMA16(af[i], bfr[j], acc[i][j]);
    __syncthreads();
  }

#pragma unroll
  for (int i = 0; i < 4; i++) {
    const int m0 = bm + wm + i * 16 + quad * 4;
#pragma unroll
    for (int j = 0; j < 4; j++) {
      const int n = bn + wn + j * 16 + l15;
      const float bv = bias[n];
      if (mode == 2) {
        // VhT[bh][dk][s]: consecutive r -> consecutive s -> 8B vector store
        int b_ = m0 >> 11, s_ = m0 & 2047;
        int h_ = n >> 6,  dk = n & 63;
        v4bf pk;
#pragma unroll
        for (int r = 0; r < 4; r++) pk[r] = (bf16)(acc[i][j][r] + bv);
        *(v4bf*)&outh[((size_t)((b_ * 16 + h_) * 64 + dk)) * 2048 + s_] = pk;
      } else {
        // mode 3: 1/sqrt(DK) * log2(e) so attn softmax is a bare v_exp
        const float sc = (mode == 3) ? 0.18033688011112042f : 1.0f;
        int h_ = n >> 6,  dk = n & 63;
#pragma unroll
        for (int r = 0; r < 4; r++) {
          int m = m0 + r;
          int b_ = m >> 11, s_ = m & 2047;
          outh[(((size_t)(b_ * 16 + h_) * 2048 + s_) << 6) + dk] =
              (bf16)((acc[i][j][r] + bv) * sc);
        }
      }
    }
  }
}

// XCD-aware swizzle (T1): physical p -> logical l = (p%8)*C + p/8 (bijective,
// count divisible by 8). Default x-fastest dispatch round-robins consecutive
// blocks across XCDs -> every XCD streams ALL 32 A-panels (8 MB/z) through its
// 4 MB L2. Swizzled: each XCD owns a contiguous row range -> working set
// (4 A-panels = 1 MB + full W = 2 MB) is L2-resident.
__global__ __launch_bounds__(256, 2) void gemm_proj_kernel(
    const bf16* qb, const bf16* kb, const bf16* vb,
    const bf16* wqb, const bf16* wkb, const bf16* wvb,
    const float* bq, const float* bk, const float* bv,
    bf16* Qh, bf16* Kh, bf16* VhT)
{
  const bf16* A; const bf16* W; const float* bias; bf16* out; int mode;
  if (blockIdx.z == 0)      { A = qb; W = wqb; bias = bq; out = Qh;  mode = 3; }
  else if (blockIdx.z == 1) { A = kb; W = wkb; bias = bk; out = Kh;  mode = 0; }
  else                      { A = vb; W = wvb; bias = bv; out = VhT; mode = 2; }
  const int p = blockIdx.y * 8 + blockIdx.x;      // 0..255 per z
  const int l = (p & 7) * 32 + (p >> 3);          // XCD k -> logical [32k, 32k+32)
  const int row = l >> 3, col = l & 7;
  gemm_bt_body(A, W, bias, out, row * 128, col * 128, mode);
}

// ---------------- final GEMM, 64x128 tile: 512 blocks = 2/CU (round-8 win) ----------
__global__ __launch_bounds__(256, 4) void gemm_final_kernel(
    const bf16* __restrict__ Ob, const bf16* __restrict__ wob,
    const float* __restrict__ bo, float* __restrict__ out)
{
  __shared__ alignas(16) bf16 As[64 * 32];
  __shared__ alignas(16) bf16 Bs[128 * 32];
  const int p = blockIdx.y * 8 + blockIdx.x;      // 0..511
  const int l = (p & 7) * 64 + (p >> 3);          // XCD k -> logical [64k, 64k+64)
  const int bm = (l >> 3) * 64, bn = (l & 7) * 128;
  const int tid = threadIdx.x;
  const int wave = tid >> 6, lane = tid & 63;
  const int quad = lane >> 4, l15 = lane & 15;
  const int wm = (wave >> 1) * 32, wn = (wave & 1) * 64;
  const int lrow = lane >> 2, lcol = (lane & 3) * 8;

  v4f acc[2][4];
#pragma unroll
  for (int i = 0; i < 2; i++)
#pragma unroll
    for (int j = 0; j < 4; j++) { v4f z = {0.f, 0.f, 0.f, 0.f}; acc[i][j] = z; }

  const bf16* gA = Ob  + (size_t)(bm + wave * 16 + lrow) * 1024 + lcol;
  const bf16* gB = wob + (size_t)(bn + wave * 32 + lrow) * 1024 + lcol;
  bf16* lA  = &As[(wave * 16) * 32];
  bf16* lB0 = &Bs[(wave * 32) * 32];
  bf16* lB1 = &Bs[(wave * 32 + 16) * 32];

  for (int k0 = 0; k0 < 1024; k0 += 32) {
    gld_lds16(gA + k0, lA);
    gld_lds16(gB + k0, lB0);
    gld_lds16(gB + 16 * 1024 + k0, lB1);
    __syncthreads();
    v8bf af[2], bfr[4];
#pragma unroll
    for (int i = 0; i < 2; i++)
      af[i] = *(const v8bf*)&As[(wm + i * 16 + l15) * 32 + quad * 8];
#pragma unroll
    for (int j = 0; j < 4; j++)
      bfr[j] = *(const v8bf*)&Bs[(wn + j * 16 + l15) * 32 + quad * 8];
#pragma unroll
    for (int i = 0; i < 2; i++)
#pragma unroll
      for (int j = 0; j < 4; j++)
        acc[i][j] = MFMA16(af[i], bfr[j], acc[i][j]);
    __syncthreads();
  }

#pragma unroll
  for (int i = 0; i < 2; i++) {
    const int m0 = bm + wm + i * 16 + quad * 4;
#pragma unroll
    for (int j = 0; j < 4; j++) {
      const int n = bn + wn + j * 16 + l15;
      const float bv = bo[n];
#pragma unroll
      for (int r = 0; r < 4; r++)
        out[(size_t)(m0 + r) * 1024 + n] = acc[i][j][r] + bv;
    }
  }
}

// ---------------- flash attention v9 (r15-proven, 70.4 us) ----------------
// Block = 2 waves on tiles (2u, 2u+1), lockstep chunk range 0..u (L1 K/V sharing).
// Closed lines (measured): key-split decomposition (r0/r10/r14/r16 -- all regress
// even with clean resources); V double-buffer (r12: latency already covered);
// >2 waves/SIMD of this body (r3/r7/r14: allocator pads min-waves ~2x -> spill).
// gy->u permutation balances each CU class at 66 chunk-units. No running max
// (scores bounded); Q pre-scaled by 0.125*log2e -> softmax is bare v_exp_f32.
// Transposed QK (r13 win): cnT = mfma(K,Q) -> S^T[k@quad*4+r][q@l15] -> P stores
// are 8 x ds_write_b64/chunk; PV reads row-major b128. Diagonal peeled.
// setprio kept (r15: neutral, free).
__global__ __launch_bounds__(128, 2) void attn_kernel(
    const bf16* __restrict__ Qh, const bf16* __restrict__ Kh,
    const bf16* __restrict__ VhT, bf16* __restrict__ Ob)
{
  __shared__ alignas(16) bf16 Ps[2][32 * 72];   // per-wave P slice [q=32][k=64 pad 72]
  const int tid = threadIdx.x;
  const int wave = tid >> 6, lane = tid & 63;
  const int quad = lane >> 4, l15 = lane & 15;
  const int bh = blockIdx.x, gy = blockIdx.y;
  const int b = bh >> 4, h = bh & 15;
  const int r8 = gy & 7, q8 = gy >> 3;
  const int u = 8 * q8 + ((q8 & 1) ? (7 - r8) : r8);
  const int qt = 2 * u + wave;                  // both waves: chunks 0..u
  const int L = u;
  const bf16* Qb = Qh + (size_t)bh * Sq * 64;
  const bf16* Kb = Kh + (size_t)bh * Sq * 64;
  const bf16* Vb = VhT + (size_t)bh * 64 * Sq;
  bf16* Pw = &Ps[wave][0];
  const int r0 = qt * 32;

  // Q fragments (pre-scaled in projection): [q=l15 row][dk=ks*32+quad*8+j]
  v8bf aq[2][2];
#pragma unroll
  for (int s = 0; s < 2; s++)
#pragma unroll
    for (int ks = 0; ks < 2; ks++)
      aq[s][ks] = *(const v8bf*)&Qb[(size_t)(r0 + s * 16 + l15) * 64 + ks * 32 + quad * 8];

  float lsumT[2];                // per-lane running sum for q-row = l15 (s halves)
  v4f o[2][4];
  lsumT[0] = 0.f; lsumT[1] = 0.f;
#pragma unroll
  for (int s = 0; s < 2; s++)
#pragma unroll
    for (int j = 0; j < 4; j++) { v4f z = {0.f, 0.f, 0.f, 0.f}; o[s][j] = z; }

  auto loadK = [&](int kb, v8bf (&BK)[4][2]) {
#pragma unroll
    for (int n = 0; n < 4; n++) {
      BK[n][0] = *(const v8bf*)&Kb[(size_t)(kb + n * 16 + l15) * 64 + quad * 8];
      BK[n][1] = *(const v8bf*)&Kb[(size_t)(kb + n * 16 + l15) * 64 + 32 + quad * 8];
    }
  };
  auto loadV = [&](int kb, v8bf (&BV)[4][2]) {
#pragma unroll
    for (int n = 0; n < 4; n++) {
      BV[n][0] = *(const v8bf*)&Vb[(size_t)(n * 16 + l15) * 2048 + kb + quad * 8];
      BV[n][1] = *(const v8bf*)&Vb[(size_t)(n * 16 + l15) * 2048 + kb + 32 + quad * 8];
    }
  };
  // diag is always a call-site literal -> constant-folded after inlining
  auto compute = [&](const v8bf (&BK)[4][2], const v8bf (&BV)[4][2], int kc, bool diag) {
    const int kbase = kc * 64;
#pragma unroll
    for (int s = 0; s < 2; s++) {
      // transposed QK: S^T[k = n*16+quad*4+r][q = l15]
      v4f cnT[4];
      __builtin_amdgcn_s_setprio(1);
#pragma unroll
      for (int n = 0; n < 4; n++) {
        v4f z = {0.f, 0.f, 0.f, 0.f};
        cnT[n] = MFMA16(BK[n][0], aq[s][0], z);
        cnT[n] = MFMA16(BK[n][1], aq[s][1], cnT[n]);
      }
      __builtin_amdgcn_s_setprio(0);
      const int qglob = r0 + s * 16 + l15;        // this lane's q-row
#pragma unroll
      for (int n = 0; n < 4; n++) {
        const int kb_n = kbase + n * 16 + quad * 4;
        v4bf pk;
#pragma unroll
        for (int r = 0; r < 4; r++) {
          float e = exp2_raw(cnT[n][r]);
          if (diag && (kb_n + r) > qglob) e = 0.f;
          lsumT[s] += e;
          pk[r] = (bf16)e;
        }
        // P[q=s*16+l15][k = n*16+quad*4 .. +3] -> single 8B vector write
        *(v4bf*)&Pw[(s * 16 + l15) * 72 + n * 16 + quad * 4] = pk;
      }
    }
    // PV: A-layout read of own wave's P (row-major [q][k], matches write layout)
#pragma unroll
    for (int s = 0; s < 2; s++) {
      v8bf ap0 = *(const v8bf*)&Pw[(s * 16 + l15) * 72 + quad * 8];
      v8bf ap1 = *(const v8bf*)&Pw[(s * 16 + l15) * 72 + 32 + quad * 8];
      __builtin_amdgcn_s_setprio(1);
#pragma unroll
      for (int j = 0; j < 4; j++) {
        o[s][j] = MFMA16(ap0, BV[j][0], o[s][j]);
        o[s][j] = MFMA16(ap1, BV[j][1], o[s][j]);
      }
      __builtin_amdgcn_s_setprio(0);
    }
  };

  v8bf bk0[4][2], bk1[4][2], bvv[4][2];
  loadK(0, bk0);
  int kc = 0;
  // main loop: non-diagonal chunks only (no mask code)
  while (kc < L) {
    loadV(kc * 64, bvv);
    loadK((kc + 1) * 64, bk1);
    compute(bk0, bvv, kc, false);
    ++kc;
    if (kc >= L) {                 // diagonal chunk is in bk1
      loadV(kc * 64, bvv);
      compute(bk1, bvv, kc, true);
      kc = -1;
      break;
    }
    loadV(kc * 64, bvv);
    loadK((kc + 1) * 64, bk0);
    compute(bk1, bvv, kc, false);
    ++kc;
  }
  if (kc >= 0) {                   // exited with diagonal chunk in bk0 (incl. L==0)
    loadV(kc * 64, bvv);
    compute(bk0, bvv, kc, true);
  }

  // epilogue: lsumT reduce across the 4 quad-lanes sharing each l15 (xor 16, 32),
  // then redistribute to o's row pattern (row q = quad*4+r held at lane l15=q).
#pragma unroll
  for (int s = 0; s < 2; s++) {
    lsumT[s] += __shfl_xor(lsumT[s], 16, 64);
    lsumT[s] += __shfl_xor(lsumT[s], 32, 64);
  }
#pragma unroll
  for (int s = 0; s < 2; s++) {
    float inv[4];
#pragma unroll
    for (int r = 0; r < 4; r++)
      inv[r] = 1.0f / __shfl(lsumT[s], quad * 4 + r, 64);
#pragma unroll
    for (int r = 0; r < 4; r++) {
      const int sg = r0 + s * 16 + quad * 4 + r;
#pragma unroll
      for (int j = 0; j < 4; j++)
        Ob[((size_t)(b * Sq + sg)) * 1024 + h * 64 + j * 16 + l15] =
            (bf16)(o[s][j][r] * inv[r]);
    }
  }
}

// ---------------- launch ----------------
extern "C" void kernel_launch(void* const* d_in, const int* in_sizes, int n_in,
                              void* d_out, int out_size, void* d_ws, size_t ws_size,
                              hipStream_t stream) {
  (void)in_sizes; (void)n_in; (void)out_size; (void)ws_size;
  const float* kin = (const float*)d_in[0];
  const float* qin = (const float*)d_in[1];
  const float* vin = (const float*)d_in[2];
  const float* wq  = (const float*)d_in[3];
  const float* bq  = (const float*)d_in[4];
  const float* wk  = (const float*)d_in[5];
  const float* bk  = (const float*)d_in[6];
  const float* wv  = (const float*)d_in[7];
  const float* bv  = (const float*)d_in[8];
  const float* wo  = (const float*)d_in[9];
  const float* bo  = (const float*)d_in[10];

  bf16* ws = (bf16*)d_ws;
  bf16* qb  = ws;
  bf16* kb  = ws + NI;
  bf16* vb  = ws + 2 * NI;
  bf16* wqb = ws + 3 * NI;
  bf16* wkb = wqb + NW;
  bf16* wvb = wqb + 2 * NW;
  bf16* wob = wqb + 3 * NW;
  bf16* Qh  = ws + 3 * NI + 4 * NW;
  bf16* Kh  = Qh + NI;
  bf16* VhT = Qh + 2 * NI;
  bf16* Ob  = Qh + 3 * NI;

  convert_kernel<<<16384, 256, 0, stream>>>(qin, kin, vin, wq, wk, wv, wo, ws);
  gemm_proj_kernel<<<dim3(8, 32, 3), 256, 0, stream>>>(
      qb, kb, vb, wqb, wkb, wvb, bq, bk, bv, Qh, Kh, VhT);
  attn_kernel<<<dim3(32, 32), 128, 0, stream>>>(Qh, Kh, VhT, Ob);
  gemm_final_kernel<<<dim3(8, 64), 256, 0, stream>>>(Ob, wob, bo, (float*)d_out);
}

// Round 19
// 249.211 us; speedup vs baseline: 1.0661x; 1.0009x over previous
//
#include <hip/hip_runtime.h>

typedef __bf16 bf16;
typedef __bf16 v8bf __attribute__((ext_vector_type(8)));
typedef __bf16 v4bf __attribute__((ext_vector_type(4)));
typedef float  v4f  __attribute__((ext_vector_type(4)));

#define MFMA16(a,b,c) __builtin_amdgcn_mfma_f32_16x16x32_bf16((a),(b),(c),0,0,0)

// B=2, S=2048, D=1024, H=16, DK=64
static constexpr int Sq = 2048;
static constexpr size_t NI = 4194304;  // B*S*D
static constexpr size_t NW = 1048576;  // D*D

__device__ __forceinline__ void gld_lds16(const void* g, void* l) {
  __builtin_amdgcn_global_load_lds(
      (__attribute__((address_space(1))) unsigned int*)g,
      (__attribute__((address_space(3))) unsigned int*)l,
      16, 0, 0);
}

// bare v_exp_f32 (2^x) via compiler intrinsic: no libm guards, hazard handled.
__device__ __forceinline__ float exp2_raw(float x) {
  return __builtin_amdgcn_exp2f(x);
}

// ---------------- convert fp32 -> bf16 (q,k,v,wq,wk,wv,wo) ----------------
__global__ __launch_bounds__(256) void convert_kernel(
    const float* __restrict__ q, const float* __restrict__ k, const float* __restrict__ v,
    const float* __restrict__ wq, const float* __restrict__ wk,
    const float* __restrict__ wv, const float* __restrict__ wo,
    bf16* __restrict__ dst)
{
  const int NI4 = 1048576;  // NI/4 = 2^20
  const int NW4 = 262144;   // NW/4 = 2^18
  int idx = blockIdx.x * 256 + threadIdx.x;   // total 4194304
  const float* src; size_t dstoff; int local;
  if (idx < 3 * NI4) {
    int a = idx >> 20; local = idx & (NI4 - 1);
    src = (a == 0) ? q : ((a == 1) ? k : v);
    dstoff = (size_t)a * NI;
  } else {
    int t = idx - 3 * NI4;
    int a = t >> 18; local = t & (NW4 - 1);
    src = (a == 0) ? wq : ((a == 1) ? wk : ((a == 2) ? wv : wo));
    dstoff = 3 * NI + (size_t)a * NW;
  }
  float4 f = ((const float4*)src)[local];
  v4bf hv = { (bf16)f.x, (bf16)f.y, (bf16)f.z, (bf16)f.w };
  *(v4bf*)(dst + dstoff + (size_t)local * 4) = hv;
}

// ---------------- 2-phase GEMM (128x128 tile): C = A(MxK) * Bw(NxK)^T + bias ------
// T3-lite (catalog "minimum 2-phase"): stage K-step t+1 into buf^1 BEFORE the
// ds_read+MFMA of buf t; ONE __syncthreads per K-step (implicit vmcnt(0) drains
// the in-flight stages). Differs from measured-null m99/m100 dbuf in the
// stage-BEFORE-compute ordering + single barrier. Race-safe: buf[cur] reads
// complete before the barrier; buf[nxt] only read after the barrier that drains
// its stage. LDS 32 KB (3 blocks/CU still fits).
// mode 0: bf16 headsplit [B,H,S,DK]; mode 3: same *0.125*log2(e) (Q pre-scale ->
// bare v_exp softmax); mode 2: bf16 VhT [B,H,DK,S] (8B stores).
__device__ __forceinline__ void gemm_bt_body(
    const bf16* __restrict__ A, const bf16* __restrict__ Bw,
    const float* __restrict__ bias, bf16* __restrict__ outh,
    int bm, int bn, int mode)
{
  __shared__ alignas(16) bf16 As[2][128 * 32];
  __shared__ alignas(16) bf16 Bs[2][128 * 32];
  const int tid = threadIdx.x;
  const int wave = tid >> 6, lane = tid & 63;
  const int quad = lane >> 4, l15 = lane & 15;
  const int wm = (wave >> 1) * 64, wn = (wave & 1) * 64;
  const int lrow = lane >> 2, lcol = (lane & 3) * 8;

  v4f acc[4][4];
#pragma unroll
  for (int i = 0; i < 4; i++)
#pragma unroll
    for (int j = 0; j < 4; j++) { v4f z = {0.f, 0.f, 0.f, 0.f}; acc[i][j] = z; }

  const bf16* gA = A  + (size_t)(bm + wave * 32 + lrow) * 1024 + lcol;
  const bf16* gB = Bw + (size_t)(bn + wave * 32 + lrow) * 1024 + lcol;
  const int oA0 = (wave * 32) * 32;
  const int oA1 = (wave * 32 + 16) * 32;

  // prologue: stage K-step 0 into buf 0, full drain
  gld_lds16(gA, &As[0][oA0]);
  gld_lds16(gA + 16 * 1024, &As[0][oA1]);
  gld_lds16(gB, &Bs[0][oA0]);
  gld_lds16(gB + 16 * 1024, &Bs[0][oA1]);
  __syncthreads();

  int cur = 0;
  for (int k0 = 0; k0 < 1024; k0 += 32) {
    const int nxt = cur ^ 1;
    if (k0 + 32 < 1024) {               // issue next-tile stages FIRST
      gld_lds16(gA + k0 + 32, &As[nxt][oA0]);
      gld_lds16(gA + 16 * 1024 + k0 + 32, &As[nxt][oA1]);
      gld_lds16(gB + k0 + 32, &Bs[nxt][oA0]);
      gld_lds16(gB + 16 * 1024 + k0 + 32, &Bs[nxt][oA1]);
    }
    v8bf af[4], bfr[4];
#pragma unroll
    for (int i = 0; i < 4; i++)
      af[i] = *(const v8bf*)&As[cur][(wm + i * 16 + l15) * 32 + quad * 8];
#pragma unroll
    for (int j = 0; j < 4; j++)
      bfr[j] = *(const v8bf*)&Bs[cur][(wn + j * 16 + l15) * 32 + quad * 8];
#pragma unroll
    for (int i = 0; i < 4; i++)
#pragma unroll
      for (int j = 0; j < 4; j++)
        acc[i][j] = MFMA16(af[i], bfr[j], acc[i][j]);
    __syncthreads();                    // one barrier/K-step: drains stages + orders reuse
    cur = nxt;
  }

#pragma unroll
  for (int i = 0; i < 4; i++) {
    const int m0 = bm + wm + i * 16 + quad * 4;
#pragma unroll
    for (int j = 0; j < 4; j++) {
      const int n = bn + wn + j * 16 + l15;
      const float bv = bias[n];
      if (mode == 2) {
        // VhT[bh][dk][s]: consecutive r -> consecutive s -> 8B vector store
        int b_ = m0 >> 11, s_ = m0 & 2047;
        int h_ = n >> 6,  dk = n & 63;
        v4bf pk;
#pragma unroll
        for (int r = 0; r < 4; r++) pk[r] = (bf16)(acc[i][j][r] + bv);
        *(v4bf*)&outh[((size_t)((b_ * 16 + h_) * 64 + dk)) * 2048 + s_] = pk;
      } else {
        // mode 3: 1/sqrt(DK) * log2(e) so attn softmax is a bare v_exp
        const float sc = (mode == 3) ? 0.18033688011112042f : 1.0f;
        int h_ = n >> 6,  dk = n & 63;
#pragma unroll
        for (int r = 0; r < 4; r++) {
          int m = m0 + r;
          int b_ = m >> 11, s_ = m & 2047;
          outh[(((size_t)(b_ * 16 + h_) * 2048 + s_) << 6) + dk] =
              (bf16)((acc[i][j][r] + bv) * sc);
        }
      }
    }
  }
}

// XCD-aware swizzle (T1, r18 win): physical p -> logical l = (p%8)*32 + p/8.
__global__ __launch_bounds__(256, 2) void gemm_proj_kernel(
    const bf16* qb, const bf16* kb, const bf16* vb,
    const bf16* wqb, const bf16* wkb, const bf16* wvb,
    const float* bq, const float* bk, const float* bv,
    bf16* Qh, bf16* Kh, bf16* VhT)
{
  const bf16* A; const bf16* W; const float* bias; bf16* out; int mode;
  if (blockIdx.z == 0)      { A = qb; W = wqb; bias = bq; out = Qh;  mode = 3; }
  else if (blockIdx.z == 1) { A = kb; W = wkb; bias = bk; out = Kh;  mode = 0; }
  else                      { A = vb; W = wvb; bias = bv; out = VhT; mode = 2; }
  const int p = blockIdx.y * 8 + blockIdx.x;      // 0..255 per z
  const int l = (p & 7) * 32 + (p >> 3);          // XCD k -> logical [32k, 32k+32)
  const int row = l >> 3, col = l & 7;
  gemm_bt_body(A, W, bias, out, row * 128, col * 128, mode);
}

// ---------------- final GEMM, 64x128 tile: 512 blocks = 2/CU (r8 win, r18 swizzle) --
__global__ __launch_bounds__(256, 4) void gemm_final_kernel(
    const bf16* __restrict__ Ob, const bf16* __restrict__ wob,
    const float* __restrict__ bo, float* __restrict__ out)
{
  __shared__ alignas(16) bf16 As[64 * 32];
  __shared__ alignas(16) bf16 Bs[128 * 32];
  const int p = blockIdx.y * 8 + blockIdx.x;      // 0..511
  const int l = (p & 7) * 64 + (p >> 3);          // XCD k -> logical [64k, 64k+64)
  const int bm = (l >> 3) * 64, bn = (l & 7) * 128;
  const int tid = threadIdx.x;
  const int wave = tid >> 6, lane = tid & 63;
  const int quad = lane >> 4, l15 = lane & 15;
  const int wm = (wave >> 1) * 32, wn = (wave & 1) * 64;
  const int lrow = lane >> 2, lcol = (lane & 3) * 8;

  v4f acc[2][4];
#pragma unroll
  for (int i = 0; i < 2; i++)
#pragma unroll
    for (int j = 0; j < 4; j++) { v4f z = {0.f, 0.f, 0.f, 0.f}; acc[i][j] = z; }

  const bf16* gA = Ob  + (size_t)(bm + wave * 16 + lrow) * 1024 + lcol;
  const bf16* gB = wob + (size_t)(bn + wave * 32 + lrow) * 1024 + lcol;
  bf16* lA  = &As[(wave * 16) * 32];
  bf16* lB0 = &Bs[(wave * 32) * 32];
  bf16* lB1 = &Bs[(wave * 32 + 16) * 32];

  for (int k0 = 0; k0 < 1024; k0 += 32) {
    gld_lds16(gA + k0, lA);
    gld_lds16(gB + k0, lB0);
    gld_lds16(gB + 16 * 1024 + k0, lB1);
    __syncthreads();
    v8bf af[2], bfr[4];
#pragma unroll
    for (int i = 0; i < 2; i++)
      af[i] = *(const v8bf*)&As[(wm + i * 16 + l15) * 32 + quad * 8];
#pragma unroll
    for (int j = 0; j < 4; j++)
      bfr[j] = *(const v8bf*)&Bs[(wn + j * 16 + l15) * 32 + quad * 8];
#pragma unroll
    for (int i = 0; i < 2; i++)
#pragma unroll
      for (int j = 0; j < 4; j++)
        acc[i][j] = MFMA16(af[i], bfr[j], acc[i][j]);
    __syncthreads();
  }

#pragma unroll
  for (int i = 0; i < 2; i++) {
    const int m0 = bm + wm + i * 16 + quad * 4;
#pragma unroll
    for (int j = 0; j < 4; j++) {
      const int n = bn + wn + j * 16 + l15;
      const float bv = bo[n];
#pragma unroll
      for (int r = 0; r < 4; r++)
        out[(size_t)(m0 + r) * 1024 + n] = acc[i][j][r] + bv;
    }
  }
}

// ---------------- flash attention v9 (r15-proven, ~70 us) ----------------
// Block = 2 waves on tiles (2u, 2u+1), lockstep chunk range 0..u (L1 K/V sharing).
// Closed lines (measured): key-split decomposition (r0/r10/r14/r16); V dbuf (r12);
// >2 waves/SIMD of this body (r3/r7/r14). Transposed QK (r13 win), diag peel,
// bare v_exp, setprio (neutral, free). attn grid is XCD-friendly by construction
// (bh%8 -> XCD -> 4 bh per XCD L2 = 2 MB K/V working set).
__global__ __launch_bounds__(128, 2) void attn_kernel(
    const bf16* __restrict__ Qh, const bf16* __restrict__ Kh,
    const bf16* __restrict__ VhT, bf16* __restrict__ Ob)
{
  __shared__ alignas(16) bf16 Ps[2][32 * 72];   // per-wave P slice [q=32][k=64 pad 72]
  const int tid = threadIdx.x;
  const int wave = tid >> 6, lane = tid & 63;
  const int quad = lane >> 4, l15 = lane & 15;
  const int bh = blockIdx.x, gy = blockIdx.y;
  const int b = bh >> 4, h = bh & 15;
  const int r8 = gy & 7, q8 = gy >> 3;
  const int u = 8 * q8 + ((q8 & 1) ? (7 - r8) : r8);
  const int qt = 2 * u + wave;                  // both waves: chunks 0..u
  const int L = u;
  const bf16* Qb = Qh + (size_t)bh * Sq * 64;
  const bf16* Kb = Kh + (size_t)bh * Sq * 64;
  const bf16* Vb = VhT + (size_t)bh * 64 * Sq;
  bf16* Pw = &Ps[wave][0];
  const int r0 = qt * 32;

  // Q fragments (pre-scaled in projection): [q=l15 row][dk=ks*32+quad*8+j]
  v8bf aq[2][2];
#pragma unroll
  for (int s = 0; s < 2; s++)
#pragma unroll
    for (int ks = 0; ks < 2; ks++)
      aq[s][ks] = *(const v8bf*)&Qb[(size_t)(r0 + s * 16 + l15) * 64 + ks * 32 + quad * 8];

  float lsumT[2];                // per-lane running sum for q-row = l15 (s halves)
  v4f o[2][4];
  lsumT[0] = 0.f; lsumT[1] = 0.f;
#pragma unroll
  for (int s = 0; s < 2; s++)
#pragma unroll
    for (int j = 0; j < 4; j++) { v4f z = {0.f, 0.f, 0.f, 0.f}; o[s][j] = z; }

  auto loadK = [&](int kb, v8bf (&BK)[4][2]) {
#pragma unroll
    for (int n = 0; n < 4; n++) {
      BK[n][0] = *(const v8bf*)&Kb[(size_t)(kb + n * 16 + l15) * 64 + quad * 8];
      BK[n][1] = *(const v8bf*)&Kb[(size_t)(kb + n * 16 + l15) * 64 + 32 + quad * 8];
    }
  };
  auto loadV = [&](int kb, v8bf (&BV)[4][2]) {
#pragma unroll
    for (int n = 0; n < 4; n++) {
      BV[n][0] = *(const v8bf*)&Vb[(size_t)(n * 16 + l15) * 2048 + kb + quad * 8];
      BV[n][1] = *(const v8bf*)&Vb[(size_t)(n * 16 + l15) * 2048 + kb + 32 + quad * 8];
    }
  };
  // diag is always a call-site literal -> constant-folded after inlining
  auto compute = [&](const v8bf (&BK)[4][2], const v8bf (&BV)[4][2], int kc, bool diag) {
    const int kbase = kc * 64;
#pragma unroll
    for (int s = 0; s < 2; s++) {
      // transposed QK: S^T[k = n*16+quad*4+r][q = l15]
      v4f cnT[4];
      __builtin_amdgcn_s_setprio(1);
#pragma unroll
      for (int n = 0; n < 4; n++) {
        v4f z = {0.f, 0.f, 0.f, 0.f};
        cnT[n] = MFMA16(BK[n][0], aq[s][0], z);
        cnT[n] = MFMA16(BK[n][1], aq[s][1], cnT[n]);
      }
      __builtin_amdgcn_s_setprio(0);
      const int qglob = r0 + s * 16 + l15;        // this lane's q-row
#pragma unroll
      for (int n = 0; n < 4; n++) {
        const int kb_n = kbase + n * 16 + quad * 4;
        v4bf pk;
#pragma unroll
        for (int r = 0; r < 4; r++) {
          float e = exp2_raw(cnT[n][r]);
          if (diag && (kb_n + r) > qglob) e = 0.f;
          lsumT[s] += e;
          pk[r] = (bf16)e;
        }
        // P[q=s*16+l15][k = n*16+quad*4 .. +3] -> single 8B vector write
        *(v4bf*)&Pw[(s * 16 + l15) * 72 + n * 16 + quad * 4] = pk;
      }
    }
    // PV: A-layout read of own wave's P (row-major [q][k], matches write layout)
#pragma unroll
    for (int s = 0; s < 2; s++) {
      v8bf ap0 = *(const v8bf*)&Pw[(s * 16 + l15) * 72 + quad * 8];
      v8bf ap1 = *(const v8bf*)&Pw[(s * 16 + l15) * 72 + 32 + quad * 8];
      __builtin_amdgcn_s_setprio(1);
#pragma unroll
      for (int j = 0; j < 4; j++) {
        o[s][j] = MFMA16(ap0, BV[j][0], o[s][j]);
        o[s][j] = MFMA16(ap1, BV[j][1], o[s][j]);
      }
      __builtin_amdgcn_s_setprio(0);
    }
  };

  v8bf bk0[4][2], bk1[4][2], bvv[4][2];
  loadK(0, bk0);
  int kc = 0;
  // main loop: non-diagonal chunks only (no mask code)
  while (kc < L) {
    loadV(kc * 64, bvv);
    loadK((kc + 1) * 64, bk1);
    compute(bk0, bvv, kc, false);
    ++kc;
    if (kc >= L) {                 // diagonal chunk is in bk1
      loadV(kc * 64, bvv);
      compute(bk1, bvv, kc, true);
      kc = -1;
      break;
    }
    loadV(kc * 64, bvv);
    loadK((kc + 1) * 64, bk0);
    compute(bk1, bvv, kc, false);
    ++kc;
  }
  if (kc >= 0) {                   // exited with diagonal chunk in bk0 (incl. L==0)
    loadV(kc * 64, bvv);
    compute(bk0, bvv, kc, true);
  }

  // epilogue: lsumT reduce across the 4 quad-lanes sharing each l15 (xor 16, 32),
  // then redistribute to o's row pattern (row q = quad*4+r held at lane l15=q).
#pragma unroll
  for (int s = 0; s < 2; s++) {
    lsumT[s] += __shfl_xor(lsumT[s], 16, 64);
    lsumT[s] += __shfl_xor(lsumT[s], 32, 64);
  }
#pragma unroll
  for (int s = 0; s < 2; s++) {
    float inv[4];
#pragma unroll
    for (int r = 0; r < 4; r++)
      inv[r] = 1.0f / __shfl(lsumT[s], quad * 4 + r, 64);
#pragma unroll
    for (int r = 0; r < 4; r++) {
      const int sg = r0 + s * 16 + quad * 4 + r;
#pragma unroll
      for (int j = 0; j < 4; j++)
        Ob[((size_t)(b * Sq + sg)) * 1024 + h * 64 + j * 16 + l15] =
            (bf16)(o[s][j][r] * inv[r]);
    }
  }
}

// ---------------- launch ----------------
extern "C" void kernel_launch(void* const* d_in, const int* in_sizes, int n_in,
                              void* d_out, int out_size, void* d_ws, size_t ws_size,
                              hipStream_t stream) {
  (void)in_sizes; (void)n_in; (void)out_size; (void)ws_size;
  const float* kin = (const float*)d_in[0];
  const float* qin = (const float*)d_in[1];
  const float* vin = (const float*)d_in[2];
  const float* wq  = (const float*)d_in[3];
  const float* bq  = (const float*)d_in[4];
  const float* wk  = (const float*)d_in[5];
  const float* bk  = (const float*)d_in[6];
  const float* wv  = (const float*)d_in[7];
  const float* bv  = (const float*)d_in[8];
  const float* wo  = (const float*)d_in[9];
  const float* bo  = (const float*)d_in[10];

  bf16* ws = (bf16*)d_ws;
  bf16* qb  = ws;
  bf16* kb  = ws + NI;
  bf16* vb  = ws + 2 * NI;
  bf16* wqb = ws + 3 * NI;
  bf16* wkb = wqb + NW;
  bf16* wvb = wqb + 2 * NW;
  bf16* wob = wqb + 3 * NW;
  bf16* Qh  = ws + 3 * NI + 4 * NW;
  bf16* Kh  = Qh + NI;
  bf16* VhT = Qh + 2 * NI;
  bf16* Ob  = Qh + 3 * NI;

  convert_kernel<<<16384, 256, 0, stream>>>(qin, kin, vin, wq, wk, wv, wo, ws);
  gemm_proj_kernel<<<dim3(8, 32, 3), 256, 0, stream>>>(
      qb, kb, vb, wqb, wkb, wvb, bq, bk, bv, Qh, Kh, VhT);
  attn_kernel<<<dim3(32, 32), 128, 0, stream>>>(Qh, Kh, VhT, Ob);
  gemm_final_kernel<<<dim3(8, 64), 256, 0, stream>>>(Ob, wob, bo, (float*)d_out);
}